// Round 9
// baseline (2054.466 us; speedup 1.0000x reference)
//
#include <hip/hip_runtime.h>

typedef unsigned int uint_t;
typedef float v2f __attribute__((ext_vector_type(2)));

#define BB 64
#define TT 1024

__device__ __forceinline__ float sigm(float x) { return 1.f / (1.f + __expf(-x)); }
__device__ __forceinline__ float tanh_f(float x) { float e = __expf(2.f * x); return 1.f - 2.f / (e + 1.f); }
__device__ __forceinline__ int finitef(float x) { return (x == x) && (fabsf(x) < 1e30f); }

// Bounded wait on an LDS flag (monotone step counter) with s_sleep backoff.
// Cap => sync bug gives wrong answer, not hang.
__device__ __forceinline__ void spinwait(volatile int* f, int v) {
  if (*f >= v) { asm volatile("" ::: "memory"); return; }
  int it = 0;
  while (*f < v && it < (1 << 15)) { __builtin_amdgcn_s_sleep(1); ++it; }
  asm volatile("" ::: "memory");
}

// x feature j of token (b,t): [e_i(0..9) | e_j(10..19) | rbf(20..29)]
__device__ __forceinline__ float feat(int b, int t, int j,
                                      const int* atom_idx, const float* bond_dist,
                                      const float* emb) {
  int ii = atom_idx[(b * TT + t) * 2 + 0];
  if (j < 10) {
    return ii ? emb[ii * 10 + j] : 0.f;
  } else if (j < 20) {
    int jj = atom_idx[(b * TT + t) * 2 + 1];
    return jj ? emb[jj * 10 + (j - 10)] : 0.f;
  } else {
    float d = bond_dist[b * TT + t];
    float c = (float)(j - 19);
    float df = c - d;
    return ii ? __expf(-df * df) : 0.f;
  }
}

// ---------------- xw0 = x @ w_ih0.T + b_ih0  (K=30, G=192, 8x g-blocked) ----------------
// One act-row read feeds 8 accumulators: DS-b32 ops per thread 1440 -> 180.
// Weight reads are wave-uniform (g0 from tid>>6) => scalar s_loads, off the DS pipe.
extern "C" __global__ void __launch_bounds__(256)
k_xw0(const int* atom_idx, const float* bond_dist, const float* emb,
      const float* w_ih0, const float* b_ih0, float* xw0) {
  int b  = blockIdx.x >> 4;
  int t0 = (blockIdx.x & 15) << 6;
  int tid = threadIdx.x;
  __shared__ float xt[64 * 31];
  for (int i = tid; i < 64 * 30; i += 256) {
    int r = i / 30, j = i % 30;
    xt[r * 31 + j] = feat(b, t0 + r, j, atom_idx, bond_dist, emb);
  }
  __syncthreads();
  int r = tid & 63, gq = tid >> 6;
  const float* ar = &xt[r * 31];
  for (int g0 = gq * 8; g0 < 192; g0 += 32) {
    float acc[8];
    #pragma unroll
    for (int j = 0; j < 8; ++j) acc[j] = b_ih0[g0 + j];
    #pragma unroll
    for (int c = 0; c < 30; ++c) {
      float a = ar[c];
      #pragma unroll
      for (int j = 0; j < 8; ++j) acc[j] += a * w_ih0[(g0 + j) * 30 + c];
    }
    #pragma unroll
    for (int j = 0; j < 8; ++j)
      xw0[((size_t)b * TT + t0 + r) * 192 + g0 + j] = acc[j];
  }
}

// ---------------- (64 rows) x (G x 64) GEMM, 8x g-blocked ----------------
__device__ __forceinline__ void gemm64b(const float* __restrict__ act_g,
                                        const float* __restrict__ w,
                                        const float* __restrict__ bias,
                                        float* al,
                                        int G, int tid,
                                        float* out, int out_rstride, size_t out_base) {
  for (int i = tid; i < 64 * 64; i += 256) {
    int r = i >> 6, c = i & 63;
    al[r * 65 + c] = act_g[r * 64 + c];
  }
  __syncthreads();
  int r = tid & 63, gq = tid >> 6;
  const float* ar = &al[r * 65];
  for (int g0 = gq * 8; g0 < G; g0 += 32) {
    float acc[8];
    #pragma unroll
    for (int j = 0; j < 8; ++j) acc[j] = bias[g0 + j];
    #pragma unroll
    for (int c = 0; c < 64; ++c) {
      float a = ar[c];
      #pragma unroll
      for (int j = 0; j < 8; ++j) acc[j] += a * w[(size_t)(g0 + j) * 64 + c];
    }
    #pragma unroll
    for (int j = 0; j < 8; ++j)
      out[out_base + (size_t)r * out_rstride + g0 + j] = acc[j];
  }
}

// Load a 64-wide weight row into 32 packed v2f registers.
__device__ __forceinline__ void loadw2(const float* p, v2f* w2) {
  const float4* p4 = (const float4*)p;
  #pragma unroll
  for (int i = 0; i < 16; ++i) {
    float4 a = p4[i];
    v2f lo; lo.x = a.x; lo.y = a.y;
    v2f hi; hi.x = a.z; hi.y = a.w;
    w2[2 * i] = lo; w2[2 * i + 1] = hi;
  }
}

// ---------------- fused GRU0+xw1 -> GRU1 : TWO-wave pipeline, one block/batch ----------------
// R8 analysis: the 3-wave version's DS pipe carried 48 b128/step (~576cy) because
// wave1 re-read h0 from LDS. But wave0 ALREADY reads h0(s-1) every step for its own
// recurrence -- the same registers can feed W_ih1.h0(s-1) for free. New split:
//   wave0: layer-0 recurrence + xw1(s-1) = W_ih1.h0(s-1)+b  (6 weight rows, ~384 VGPR)
//   wave1: layer-1 recurrence consuming xwring, writes g1 to global.
// DS/step drops to ~32 b128; xwring depth 16 gives slack; monotone flags + s_sleep.
extern "C" __global__ void __launch_bounds__(128, 1)
k_grufused(const float* xw0, const float* w_hh0, const float* b_hh0,
           const float* w_ih1, const float* b_ih1,
           const float* w_hh1, const float* b_hh1, float* g1out) {
  int b    = blockIdx.x;
  int lane = threadIdx.x & 63;
  int wid  = threadIdx.x >> 6;
  __shared__ __align__(16) float h0pp[2][64];     // wave0-private double buffer
  __shared__ __align__(16) float xwring[16][192];
  __shared__ __align__(16) float h1pp[2][64];
  __shared__ int flags[2];        // w0d: highest xw1 index ready; w1d: wave1 progress

  if (threadIdx.x < 2) flags[threadIdx.x] = -1;
  if (wid == 0) h0pp[0][lane] = 0.f;   // h0(-1) = 0
  if (wid == 1) h1pp[0][lane] = 0.f;   // h1(-1) = 0
  __syncthreads();

  volatile int* w0d = &flags[0];
  volatile int* w1d = &flags[1];

  if (wid == 0) {
    // ---- layer-0 recurrence + xw1 on the same h0 read ----
    v2f wr2[32], wz2[32], wn2[32];   // W_hh0 rows
    v2f ur2[32], uz2[32], un2[32];   // W_ih1 rows
    loadw2(w_hh0 + (size_t)lane * 64,         wr2);
    loadw2(w_hh0 + (size_t)(64 + lane) * 64,  wz2);
    loadw2(w_hh0 + (size_t)(128 + lane) * 64, wn2);
    loadw2(w_ih1 + (size_t)lane * 64,         ur2);
    loadw2(w_ih1 + (size_t)(64 + lane) * 64,  uz2);
    loadw2(w_ih1 + (size_t)(128 + lane) * 64, un2);
    float br = b_hh0[lane], bz = b_hh0[64 + lane], bn = b_hh0[128 + lane];
    float cr = b_ih1[lane], cz = b_ih1[64 + lane], cn = b_ih1[128 + lane];
    float hv = 0.f;
    const float* xwb = xw0 + (size_t)b * TT * 192;
    float xr0 = xwb[      lane], xz0 = xwb[ 64 + lane], xn0 = xwb[128 + lane];
    float xr1 = xwb[192 + lane], xz1 = xwb[256 + lane], xn1 = xwb[320 + lane];
    float xr2 = xwb[384 + lane], xz2 = xwb[448 + lane], xn2 = xwb[512 + lane];
    float xr3 = xwb[576 + lane], xz3 = xwb[640 + lane], xn3 = xwb[704 + lane];

    auto gstep = [&](int s, float xr, float xz, float xn) {
      const float4* hp4 = (const float4*)h0pp[s & 1];     // h0(s-1)
      v2f ar_; ar_.x = br; ar_.y = 0.f;
      v2f az_; az_.x = bz; az_.y = 0.f;
      v2f an_; an_.x = bn; an_.y = 0.f;
      v2f ur_; ur_.x = cr; ur_.y = 0.f;
      v2f uz_; uz_.x = cz; uz_.y = 0.f;
      v2f un_; un_.x = cn; un_.y = 0.f;
      #pragma unroll
      for (int i = 0; i < 16; ++i) {
        float4 h4 = hp4[i];
        v2f hlo; hlo.x = h4.x; hlo.y = h4.y;
        v2f hhi; hhi.x = h4.z; hhi.y = h4.w;
        ar_ += wr2[2*i] * hlo; ar_ += wr2[2*i+1] * hhi;
        az_ += wz2[2*i] * hlo; az_ += wz2[2*i+1] * hhi;
        an_ += wn2[2*i] * hlo; an_ += wn2[2*i+1] * hhi;
        ur_ += ur2[2*i] * hlo; ur_ += ur2[2*i+1] * hhi;
        uz_ += uz2[2*i] * hlo; uz_ += uz2[2*i+1] * hhi;
        un_ += un2[2*i] * hlo; un_ += un2[2*i+1] * hhi;
      }
      float r = sigm(xr + (ar_.x + ar_.y));
      float z = sigm(xz + (az_.x + az_.y));
      float n = tanh_f(xn + r * (an_.x + an_.y));
      hv = (1.f - z) * n + z * hv;
      h0pp[(s + 1) & 1][lane] = hv;
      if (s > 0) {                       // xw1(s-1) = U.h0(s-1) + b_ih1
        xwring[(s - 1) & 15][lane]       = ur_.x + ur_.y;
        xwring[(s - 1) & 15][64 + lane]  = uz_.x + uz_.y;
        xwring[(s - 1) & 15][128 + lane] = un_.x + un_.y;
      }
    };
    auto pf = [&](int s, float& a, float& bb_, float& c) {
      const float* xp = xwb + (size_t)s * 192;
      a = xp[lane]; bb_ = xp[64 + lane]; c = xp[128 + lane];
    };

    for (int s0 = 0; s0 < TT; s0 += 4) {
      // group writes xwring slots (s0-1..s0+2)&15, last used by xw1(s0-17..s0-14)
      if (s0 >= 16) spinwait(w1d, s0 - 14);
      bool dopf = (s0 < TT - 4);
      gstep(s0 + 0, xr0, xz0, xn0); if (dopf) pf(s0 + 4, xr0, xz0, xn0);
      gstep(s0 + 1, xr1, xz1, xn1); if (dopf) pf(s0 + 5, xr1, xz1, xn1);
      gstep(s0 + 2, xr2, xz2, xn2); if (dopf) pf(s0 + 6, xr2, xz2, xn2);
      gstep(s0 + 3, xr3, xz3, xn3); if (dopf) pf(s0 + 7, xr3, xz3, xn3);
      asm volatile("" ::: "memory");
      if (lane == 0) *w0d = s0 + 2;     // xw1 ready through s0+2
    }
    // epilogue: xw1(TT-1) from h0(TT-1)
    {
      const float4* hp4 = (const float4*)h0pp[TT & 1];
      v2f ur_; ur_.x = cr; ur_.y = 0.f;
      v2f uz_; uz_.x = cz; uz_.y = 0.f;
      v2f un_; un_.x = cn; un_.y = 0.f;
      #pragma unroll
      for (int i = 0; i < 16; ++i) {
        float4 h4 = hp4[i];
        v2f hlo; hlo.x = h4.x; hlo.y = h4.y;
        v2f hhi; hhi.x = h4.z; hhi.y = h4.w;
        ur_ += ur2[2*i] * hlo; ur_ += ur2[2*i+1] * hhi;
        uz_ += uz2[2*i] * hlo; uz_ += uz2[2*i+1] * hhi;
        un_ += un2[2*i] * hlo; un_ += un2[2*i+1] * hhi;
      }
      xwring[(TT - 1) & 15][lane]       = ur_.x + ur_.y;
      xwring[(TT - 1) & 15][64 + lane]  = uz_.x + uz_.y;
      xwring[(TT - 1) & 15][128 + lane] = un_.x + un_.y;
      asm volatile("" ::: "memory");
      if (lane == 0) *w0d = TT - 1;
    }
  } else {
    // ---- layer-1 recurrence ----
    v2f wr2[32], wz2[32], wn2[32];
    loadw2(w_hh1 + (size_t)lane * 64,         wr2);
    loadw2(w_hh1 + (size_t)(64 + lane) * 64,  wz2);
    loadw2(w_hh1 + (size_t)(128 + lane) * 64, wn2);
    float br = b_hh1[lane], bz = b_hh1[64 + lane], bn = b_hh1[128 + lane];
    float hv = 0.f;
    float* houtb = g1out + (size_t)b * TT * 64 + lane;

    for (int t0 = 0; t0 < TT; t0 += 4) {
      spinwait(w0d, t0 + 3);                   // xw1(t0..t0+3) ready
      #pragma unroll
      for (int k = 0; k < 4; ++k) {
        int t = t0 + k;
        float xr = xwring[t & 15][lane];
        float xz = xwring[t & 15][64 + lane];
        float xn = xwring[t & 15][128 + lane];
        const float4* hp4 = (const float4*)h1pp[t & 1];
        v2f ar_; ar_.x = br; ar_.y = 0.f;
        v2f az_; az_.x = bz; az_.y = 0.f;
        v2f an_; an_.x = bn; an_.y = 0.f;
        #pragma unroll
        for (int i = 0; i < 16; ++i) {
          float4 h4 = hp4[i];
          v2f hlo; hlo.x = h4.x; hlo.y = h4.y;
          v2f hhi; hhi.x = h4.z; hhi.y = h4.w;
          ar_ += wr2[2*i] * hlo; ar_ += wr2[2*i+1] * hhi;
          az_ += wz2[2*i] * hlo; az_ += wz2[2*i+1] * hhi;
          an_ += wn2[2*i] * hlo; an_ += wn2[2*i+1] * hhi;
        }
        float r = sigm(xr + (ar_.x + ar_.y));
        float z = sigm(xz + (az_.x + az_.y));
        float n = tanh_f(xn + r * (an_.x + an_.y));
        hv = (1.f - z) * n + z * hv;
        h1pp[(t + 1) & 1][lane] = hv;
        houtb[(size_t)t * 64] = hv;            // fire-and-forget
      }
      asm volatile("" ::: "memory");
      if (lane == 0) *w1d = t0 + 3;
    }
  }
}

// ---------------- MHA1 qkv projection (K=64, G=192, 8x g-blocked) -> head-major f32 ----------------
extern "C" __global__ void __launch_bounds__(256)
k_qkv(const float* g1, const float* in_w1, const float* in_b1,
      float* q1, float* k1, float* v1) {
  int b  = blockIdx.x >> 4;
  int t0 = (blockIdx.x & 15) << 6;
  int tid = threadIdx.x;
  __shared__ float al[64 * 65];
  const float* act = g1 + ((size_t)b * TT + t0) * 64;
  for (int i = tid; i < 64 * 64; i += 256) {
    int r = i >> 6, c = i & 63;
    al[r * 65 + c] = act[r * 64 + c];
  }
  __syncthreads();
  int r = tid & 63, gq = tid >> 6;
  const float* ar = &al[r * 65];
  for (int g0 = gq * 8; g0 < 192; g0 += 32) {
    float acc[8];
    #pragma unroll
    for (int j = 0; j < 8; ++j) acc[j] = in_b1[g0 + j];
    #pragma unroll
    for (int c = 0; c < 64; ++c) {
      float a = ar[c];
      #pragma unroll
      for (int j = 0; j < 8; ++j) acc[j] += a * in_w1[(size_t)(g0 + j) * 64 + c];
    }
    int p = g0 / 64;            // 0=q 1=k 2=v (8-chunks never cross a 64-boundary)
    float* outp = (p == 0) ? q1 : ((p == 1) ? k1 : v1);
    #pragma unroll
    for (int j = 0; j < 8; ++j) {
      int rem = (g0 - p * 64) + j;
      int hd = rem >> 5, d = rem & 31;
      outp[(((size_t)b * 2 + hd) * TT + t0 + r) * 32 + d] = acc[j];
    }
  }
}

// ---------------- MHA1 flash attention, key-split S=2, TWO q-rows per thread ----------------
extern "C" __global__ void __launch_bounds__(256, 2)
k_attn(const float* q1, const float* k1, const float* v1, float* po, float* ml) {
  int gid = blockIdx.x;          // 512 blocks: b(6)|h(1)|seg(1)|qb(1)
  int b   = gid >> 3;
  int h   = (gid >> 2) & 1;
  int seg = (gid >> 1) & 1;
  int qb  = gid & 1;
  int tid = threadIdx.x;
  int tq0 = qb * 512 + tid;      // rows tq0 and tq0+256
  __shared__ __align__(16) float Kt[64 * 32];
  __shared__ __align__(16) float Vt[64 * 32];
  float qa[32], qc[32], oa[32], oc[32];
  const float* qp0 = q1 + (((size_t)b * 2 + h) * TT + tq0) * 32;
  const float* qp1 = qp0 + 256 * 32;
  #pragma unroll
  for (int i = 0; i < 8; ++i) {
    float4 v0 = ((const float4*)qp0)[i];
    float4 v1r = ((const float4*)qp1)[i];
    qa[4*i] = v0.x; qa[4*i+1] = v0.y; qa[4*i+2] = v0.z; qa[4*i+3] = v0.w;
    qc[4*i] = v1r.x; qc[4*i+1] = v1r.y; qc[4*i+2] = v1r.z; qc[4*i+3] = v1r.w;
  }
  #pragma unroll
  for (int i = 0; i < 32; ++i) { oa[i] = 0.f; oc[i] = 0.f; }
  float m0 = -1e30f, l0 = 0.f, m1 = -1e30f, l1 = 0.f;
  const float scale = 0.17677669529663687f;   // 1/sqrt(32)
  const float4* kb = (const float4*)(k1 + ((size_t)b * 2 + h) * TT * 32);
  const float4* vb = (const float4*)(v1 + ((size_t)b * 2 + h) * TT * 32);
  int k0 = seg << 9;                           // seg*512
  for (int kt = k0; kt < k0 + 512; kt += 64) {
    __syncthreads();
    ((float4*)Kt)[tid]       = kb[kt * 8 + tid];
    ((float4*)Kt)[tid + 256] = kb[kt * 8 + tid + 256];
    ((float4*)Vt)[tid]       = vb[kt * 8 + tid];
    ((float4*)Vt)[tid + 256] = vb[kt * 8 + tid + 256];
    __syncthreads();
    #pragma unroll 1
    for (int c0 = 0; c0 < 64; c0 += 8) {
      float sv0[8], sv1[8];
      #pragma unroll
      for (int j = 0; j < 8; ++j) {
        const float4* kr = (const float4*)&Kt[(c0 + j) * 32];
        float a0 = 0, a1 = 0, c0a = 0, c1a = 0;
        #pragma unroll
        for (int i = 0; i < 8; ++i) {
          float4 kv = kr[i];                       // one broadcast read, 2 q-rows
          a0 += qa[4*i]   * kv.x; a1 += qa[4*i+1] * kv.y;
          a0 += qa[4*i+2] * kv.z; a1 += qa[4*i+3] * kv.w;
          c0a += qc[4*i]   * kv.x; c1a += qc[4*i+1] * kv.y;
          c0a += qc[4*i+2] * kv.z; c1a += qc[4*i+3] * kv.w;
        }
        sv0[j] = (a0 + a1) * scale;
        sv1[j] = (c0a + c1a) * scale;
      }
      float cm0 = sv0[0], cm1 = sv1[0];
      #pragma unroll
      for (int j = 1; j < 8; ++j) { cm0 = fmaxf(cm0, sv0[j]); cm1 = fmaxf(cm1, sv1[j]); }
      float mn0 = fmaxf(m0, cm0), mn1 = fmaxf(m1, cm1);
      float al0 = __expf(m0 - mn0), al1 = __expf(m1 - mn1);
      float ps0 = 0.f, ps1 = 0.f;
      #pragma unroll
      for (int j = 0; j < 8; ++j) {
        sv0[j] = __expf(sv0[j] - mn0); ps0 += sv0[j];
        sv1[j] = __expf(sv1[j] - mn1); ps1 += sv1[j];
      }
      l0 = l0 * al0 + ps0; m0 = mn0;
      l1 = l1 * al1 + ps1; m1 = mn1;
      #pragma unroll
      for (int i = 0; i < 8; ++i) {
        float4 A, C;
        A.x = oa[4*i] * al0; A.y = oa[4*i+1] * al0; A.z = oa[4*i+2] * al0; A.w = oa[4*i+3] * al0;
        C.x = oc[4*i] * al1; C.y = oc[4*i+1] * al1; C.z = oc[4*i+2] * al1; C.w = oc[4*i+3] * al1;
        #pragma unroll
        for (int j = 0; j < 8; ++j) {
          float4 vv = *(const float4*)&Vt[(c0 + j) * 32 + 4 * i];   // shared read
          A.x += sv0[j] * vv.x; A.y += sv0[j] * vv.y; A.z += sv0[j] * vv.z; A.w += sv0[j] * vv.w;
          C.x += sv1[j] * vv.x; C.y += sv1[j] * vv.y; C.z += sv1[j] * vv.z; C.w += sv1[j] * vv.w;
        }
        oa[4*i] = A.x; oa[4*i+1] = A.y; oa[4*i+2] = A.z; oa[4*i+3] = A.w;
        oc[4*i] = C.x; oc[4*i+1] = C.y; oc[4*i+2] = C.z; oc[4*i+3] = C.w;
      }
    }
  }
  size_t rb0 = (((size_t)(b * 2 + h)) * 2 + seg) * TT + tq0;
  size_t rb1 = rb0 + 256;
  float* op0 = po + rb0 * 32;
  float* op1 = po + rb1 * 32;
  #pragma unroll
  for (int i = 0; i < 8; ++i) {
    float4 s0; s0.x = oa[4*i]; s0.y = oa[4*i+1]; s0.z = oa[4*i+2]; s0.w = oa[4*i+3];
    float4 s1; s1.x = oc[4*i]; s1.y = oc[4*i+1]; s1.z = oc[4*i+2]; s1.w = oc[4*i+3];
    ((float4*)op0)[i] = s0;
    ((float4*)op1)[i] = s1;
  }
  ml[rb0 * 2 + 0] = m0; ml[rb0 * 2 + 1] = l0;
  ml[rb1 * 2 + 0] = m1; ml[rb1 * 2 + 1] = l1;
}

// ---------------- combine the two key-segments -> attnO [b][t][64] ----------------
extern "C" __global__ void __launch_bounds__(256)
k_attn_comb(const float* po, const float* ml, float* attnO) {
  int row = blockIdx.x * 256 + threadIdx.x;   // 0 .. 64*2*1024-1
  int bh = row >> 10;
  int t  = row & 1023;
  int b = bh >> 1, h = bh & 1;
  size_t r0 = ((size_t)bh * 2 + 0) * TT + t;
  size_t r1 = ((size_t)bh * 2 + 1) * TT + t;
  float m0 = ml[r0 * 2], l0 = ml[r0 * 2 + 1];
  float m1 = ml[r1 * 2], l1 = ml[r1 * 2 + 1];
  float m = fmaxf(m0, m1);
  float w0 = __expf(m0 - m), w1 = __expf(m1 - m);
  float inv = 1.f / (w0 * l0 + w1 * l1);
  w0 *= inv; w1 *= inv;
  const float4* p0 = (const float4*)(po + r0 * 32);
  const float4* p1 = (const float4*)(po + r1 * 32);
  float* op = attnO + ((size_t)b * TT + t) * 64 + h * 32;
  #pragma unroll
  for (int i = 0; i < 8; ++i) {
    float4 a = p0[i], c = p1[i], r;
    r.x = a.x * w0 + c.x * w1; r.y = a.y * w0 + c.y * w1;
    r.z = a.z * w0 + c.z * w1; r.w = a.w * w0 + c.w * w1;
    ((float4*)op)[i] = r;
  }
}

// ---------------- MHA1 output projection (K=64, G=64, 8x g-blocked) ----------------
extern "C" __global__ void __launch_bounds__(256)
k_oproj(const float* attnO, const float* out_w1, const float* out_b1, float* a1) {
  int b  = blockIdx.x >> 4;
  int t0 = (blockIdx.x & 15) << 6;
  __shared__ float al[64 * 65];
  gemm64b(attnO + ((size_t)b * TT + t0) * 64, out_w1, out_b1, al, 64, threadIdx.x,
          a1, 64, ((size_t)b * TT + t0) * 64);
}

// ---------------- MHA2: only the last query row matters -> scores s2 + values v2 ----------------
extern "C" __global__ void __launch_bounds__(256)
k_mha2kv(const float* a1, const float* in_w2, const float* in_b2,
         float* s2, float* v2) {
  int b  = blockIdx.x >> 4;
  int t0 = (blockIdx.x & 15) << 6;
  int tid = threadIdx.x;
  __shared__ float a1r[64 * 65];
  __shared__ float q2s[64];
  __shared__ float alast[64];
  if (tid < 64) alast[tid] = a1[((size_t)b * TT + (TT - 1)) * 64 + tid];
  for (int i = tid; i < 4096; i += 256) {
    int r = i >> 6, e = i & 63;
    a1r[r * 65 + e] = a1[((size_t)b * TT + t0 + r) * 64 + e];
  }
  __syncthreads();
  if (tid < 64) {
    float acc = in_b2[tid];
    const float* wr = in_w2 + (size_t)tid * 64;
    #pragma unroll
    for (int e = 0; e < 64; ++e) acc += alast[e] * wr[e];
    q2s[tid] = acc;
  }
  __syncthreads();
  int tt = tid & 63;
  int role = tid >> 6;
  const float* ar = &a1r[tt * 65];
  const float scale = 0.17677669529663687f;
  if (role < 2) {
    float s = 0.f;
    for (int d = 0; d < 32; ++d) {
      int row = 64 + role * 32 + d;
      const float* wr = in_w2 + (size_t)row * 64;
      float acc = in_b2[row];
      #pragma unroll
      for (int e = 0; e < 64; ++e) acc += ar[e] * wr[e];
      s += q2s[row - 64] * acc;
    }
    s2[((size_t)b * 2 + role) * TT + t0 + tt] = s * scale;
  } else {
    int half = role - 2;
    for (int d = 0; d < 32; ++d) {
      int vd = half * 32 + d;
      int row = 128 + vd;
      const float* wr = in_w2 + (size_t)row * 64;
      float acc = in_b2[row];
      #pragma unroll
      for (int e = 0; e < 64; ++e) acc += ar[e] * wr[e];
      v2[((size_t)b * TT + t0 + tt) * 64 + vd] = acc;
    }
  }
}

// ---------------- MHA2 softmax+PV, out-proj, final MLP ----------------
extern "C" __global__ void __launch_bounds__(256)
k_final(const float* s2, const float* v2,
        const float* out_w2, const float* out_b2,
        const float* w_l, const float* b_l,
        const float* w_l1, const float* b_l1,
        float* out) {
  int b = blockIdx.x;
  int tid = threadIdx.x;
  __shared__ float sm[2 * 1024];
  __shared__ float red[8];
  __shared__ float invl[2];
  __shared__ float opart[4 * 64];
  __shared__ float of[64];
  __shared__ float a2[64];
  __shared__ float hbuf[32];
  __shared__ int bad;
  if (tid == 0) bad = 0;
  for (int i = tid; i < 2048; i += 256) sm[i] = s2[(size_t)b * 2 * TT + i];
  __syncthreads();
  int lane = tid & 63;
  int wid = tid >> 6;
  for (int hh = 0; hh < 2; ++hh) {
    float mx = -1e30f;
    for (int i = tid; i < 1024; i += 256) mx = fmaxf(mx, sm[hh * 1024 + i]);
    #pragma unroll
    for (int off = 32; off > 0; off >>= 1) mx = fmaxf(mx, __shfl_down(mx, off));
    if (lane == 0) red[wid] = mx;
    __syncthreads();
    if (tid == 0) red[4] = fmaxf(fmaxf(red[0], red[1]), fmaxf(red[2], red[3]));
    __syncthreads();
    mx = red[4];
    float s = 0.f;
    for (int i = tid; i < 1024; i += 256) {
      float e = __expf(sm[hh * 1024 + i] - mx);
      sm[hh * 1024 + i] = e;
      s += e;
    }
    #pragma unroll
    for (int off = 32; off > 0; off >>= 1) s += __shfl_down(s, off);
    if (lane == 0) red[wid] = s;
    __syncthreads();
    if (tid == 0) invl[hh] = 1.f / (red[0] + red[1] + red[2] + red[3]);
    __syncthreads();
  }
  {
    int dp = tid & 63;
    int part = tid >> 6;
    int hh = dp >> 5;
    float acc = 0.f;
    for (int t = part * 256; t < part * 256 + 256; ++t)
      acc += sm[hh * 1024 + t] * v2[((size_t)b * TT + t) * 64 + dp];
    opart[part * 64 + dp] = acc;
  }
  __syncthreads();
  if (tid < 64) {
    float o = (opart[tid] + opart[64 + tid] + opart[128 + tid] + opart[192 + tid]) * invl[tid >> 5];
    of[tid] = o;
    if (!finitef(o)) bad = 1;
  }
  __syncthreads();
  if (tid < 64) {
    float acc = out_b2[tid];
    const float* wr = out_w2 + (size_t)tid * 64;
    #pragma unroll
    for (int d = 0; d < 64; ++d) acc += of[d] * wr[d];
    a2[tid] = acc;
  }
  __syncthreads();
  if (tid < 32) {
    float acc = b_l[tid];
    const float* wr = w_l + (size_t)tid * 64;
    #pragma unroll
    for (int e = 0; e < 64; ++e) acc += a2[e] * wr[e];
    hbuf[tid] = fmaxf(acc, 0.f);
  }
  __syncthreads();
  if (tid == 0) {
    float acc = b_l1[0];
    #pragma unroll
    for (int j = 0; j < 32; ++j) acc += hbuf[j] * w_l1[j];
    out[b] = bad ? 777.0f : acc;
  }
}

extern "C" void kernel_launch(void* const* d_in, const int* in_sizes, int n_in,
                              void* d_out, int out_size, void* d_ws, size_t ws_size,
                              hipStream_t stream) {
  const int*   atom_idx  = (const int*)d_in[0];
  const float* bond_dist = (const float*)d_in[1];
  const float* emb       = (const float*)d_in[2];
  const float* w_ih0     = (const float*)d_in[3];
  const float* w_hh0     = (const float*)d_in[4];
  const float* b_ih0     = (const float*)d_in[5];
  const float* b_hh0     = (const float*)d_in[6];
  const float* w_ih1     = (const float*)d_in[7];
  const float* w_hh1     = (const float*)d_in[8];
  const float* b_ih1     = (const float*)d_in[9];
  const float* b_hh1     = (const float*)d_in[10];
  const float* in_w1     = (const float*)d_in[11];
  const float* in_b1     = (const float*)d_in[12];
  const float* out_w1    = (const float*)d_in[13];
  const float* out_b1    = (const float*)d_in[14];
  const float* in_w2     = (const float*)d_in[15];
  const float* in_b2     = (const float*)d_in[16];
  const float* out_w2    = (const float*)d_in[17];
  const float* out_b2    = (const float*)d_in[18];
  const float* w_l       = (const float*)d_in[19];
  const float* b_l       = (const float*)d_in[20];
  const float* w_l1      = (const float*)d_in[21];
  const float* b_l1      = (const float*)d_in[22];

  // Arena plan (84,410,368 B total), all f32:
  //   X @ 0        (50.3 MB): xw0 -> {q,k,v | po} -> v2
  //   A @ 50331648 (16.8 MB): attnO
  //   B @ 67108864 (16.8 MB): g1 -> ml (2MB, during attn) -> a1
  //   D @ 83886080 (0.5 MB):  s2
  char* ws = (char*)d_ws;
  float* X  = (float*)(ws);
  float* A  = (float*)(ws + 50331648);
  float* Bq = (float*)(ws + 67108864);
  float* D  = (float*)(ws + 83886080);
  float* q1 = X;
  float* k1 = X + 4194304;
  float* v1 = X + 8388608;
  float* po = (float*)(ws + 16777216);   // [bh][seg][t][32] = 33,554,432 B, ends exactly at A
  float* ml = Bq;                        // [bh][seg][t][2]  = 2 MB, dead before oproj writes a1

  k_xw0      <<<dim3(1024), dim3(256), 0, stream>>>(atom_idx, bond_dist, emb, w_ih0, b_ih0, X);
  k_grufused <<<dim3(64),   dim3(128), 0, stream>>>(X, w_hh0, b_hh0, w_ih1, b_ih1, w_hh1, b_hh1, Bq);
  k_qkv      <<<dim3(1024), dim3(256), 0, stream>>>(Bq, in_w1, in_b1, q1, k1, v1);
  k_attn     <<<dim3(512),  dim3(256), 0, stream>>>(q1, k1, v1, po, ml);
  k_attn_comb<<<dim3(512),  dim3(256), 0, stream>>>(po, ml, A);
  k_oproj    <<<dim3(1024), dim3(256), 0, stream>>>(A, out_w1, out_b1, Bq);
  k_mha2kv   <<<dim3(1024), dim3(256), 0, stream>>>(Bq, in_w2, in_b2, D, X);
  k_final    <<<dim3(64),   dim3(256), 0, stream>>>(D, X, out_w2, out_b2, w_l, b_l, w_l1, b_l1, (float*)d_out);
}

// Round 10
// 1341.880 us; speedup vs baseline: 1.5310x; 1.5310x over previous
//
#include <hip/hip_runtime.h>

typedef unsigned int uint_t;
typedef float v2f __attribute__((ext_vector_type(2)));

#define BB 64
#define TT 1024

__device__ __forceinline__ float sigm(float x) { return 1.f / (1.f + __expf(-x)); }
__device__ __forceinline__ float tanh_f(float x) { float e = __expf(2.f * x); return 1.f - 2.f / (e + 1.f); }
__device__ __forceinline__ int finitef(float x) { return (x == x) && (fabsf(x) < 1e30f); }

// Bounded wait on an LDS flag (monotone step counter) with s_sleep backoff.
// Cap => sync bug gives wrong answer, not hang.
__device__ __forceinline__ void spinwait(volatile int* f, int v) {
  if (*f >= v) { asm volatile("" ::: "memory"); return; }
  int it = 0;
  while (*f < v && it < (1 << 15)) { __builtin_amdgcn_s_sleep(1); ++it; }
  asm volatile("" ::: "memory");
}

// x feature j of token (b,t): [e_i(0..9) | e_j(10..19) | rbf(20..29)]
__device__ __forceinline__ float feat(int b, int t, int j,
                                      const int* atom_idx, const float* bond_dist,
                                      const float* emb) {
  int ii = atom_idx[(b * TT + t) * 2 + 0];
  if (j < 10) {
    return ii ? emb[ii * 10 + j] : 0.f;
  } else if (j < 20) {
    int jj = atom_idx[(b * TT + t) * 2 + 1];
    return jj ? emb[jj * 10 + (j - 10)] : 0.f;
  } else {
    float d = bond_dist[b * TT + t];
    float c = (float)(j - 19);
    float df = c - d;
    return ii ? __expf(-df * df) : 0.f;
  }
}

// ---------------- xw0 = x @ w_ih0.T + b_ih0  (K=30, G=192, 8x g-blocked) ----------------
extern "C" __global__ void __launch_bounds__(256)
k_xw0(const int* atom_idx, const float* bond_dist, const float* emb,
      const float* w_ih0, const float* b_ih0, float* xw0) {
  int b  = blockIdx.x >> 4;
  int t0 = (blockIdx.x & 15) << 6;
  int tid = threadIdx.x;
  __shared__ float xt[64 * 31];
  for (int i = tid; i < 64 * 30; i += 256) {
    int r = i / 30, j = i % 30;
    xt[r * 31 + j] = feat(b, t0 + r, j, atom_idx, bond_dist, emb);
  }
  __syncthreads();
  int r = tid & 63, gq = tid >> 6;
  const float* ar = &xt[r * 31];
  for (int g0 = gq * 8; g0 < 192; g0 += 32) {
    float acc[8];
    #pragma unroll
    for (int j = 0; j < 8; ++j) acc[j] = b_ih0[g0 + j];
    #pragma unroll
    for (int c = 0; c < 30; ++c) {
      float a = ar[c];
      #pragma unroll
      for (int j = 0; j < 8; ++j) acc[j] += a * w_ih0[(g0 + j) * 30 + c];
    }
    #pragma unroll
    for (int j = 0; j < 8; ++j)
      xw0[((size_t)b * TT + t0 + r) * 192 + g0 + j] = acc[j];
  }
}

// ---------------- (64 rows) x (G x 64) GEMM, 8x g-blocked ----------------
__device__ __forceinline__ void gemm64b(const float* __restrict__ act_g,
                                        const float* __restrict__ w,
                                        const float* __restrict__ bias,
                                        float* al,
                                        int G, int tid,
                                        float* out, int out_rstride, size_t out_base) {
  for (int i = tid; i < 64 * 64; i += 256) {
    int r = i >> 6, c = i & 63;
    al[r * 65 + c] = act_g[r * 64 + c];
  }
  __syncthreads();
  int r = tid & 63, gq = tid >> 6;
  const float* ar = &al[r * 65];
  for (int g0 = gq * 8; g0 < G; g0 += 32) {
    float acc[8];
    #pragma unroll
    for (int j = 0; j < 8; ++j) acc[j] = bias[g0 + j];
    #pragma unroll
    for (int c = 0; c < 64; ++c) {
      float a = ar[c];
      #pragma unroll
      for (int j = 0; j < 8; ++j) acc[j] += a * w[(size_t)(g0 + j) * 64 + c];
    }
    #pragma unroll
    for (int j = 0; j < 8; ++j)
      out[out_base + (size_t)r * out_rstride + g0 + j] = acc[j];
  }
}

// Load a 64-wide weight row into 32 packed v2f registers.
__device__ __forceinline__ void loadw2(const float* p, v2f* w2) {
  const float4* p4 = (const float4*)p;
  #pragma unroll
  for (int i = 0; i < 16; ++i) {
    float4 a = p4[i];
    v2f lo; lo.x = a.x; lo.y = a.y;
    v2f hi; hi.x = a.z; hi.y = a.w;
    w2[2 * i] = lo; w2[2 * i + 1] = hi;
  }
}

// ---------------- fused GRU0 -> xw1 -> GRU1 : 3-stage wave pipeline (R8-proven, 604us) ----------------
// R9 lesson: merging xw1 into wave0 needs ~420 VGPR; compiler caps at 248 and spills
// the weight arrays into the serial loop (604->1344us). Reverted to the 3-wave split
// (124 VGPR, fits): wave0 GRU0, wave1 xw1, wave2 GRU1; depth-16 rings; packed v2f math.
extern "C" __global__ void __launch_bounds__(192, 1)
k_grufused(const float* xw0, const float* w_hh0, const float* b_hh0,
           const float* w_ih1, const float* b_ih1,
           const float* w_hh1, const float* b_hh1, float* g1out) {
  int b    = blockIdx.x;
  int lane = threadIdx.x & 63;
  int wid  = threadIdx.x >> 6;
  __shared__ __align__(16) float h0ring[16][64];
  __shared__ __align__(16) float xwring[16][192];
  __shared__ __align__(16) float h1pp[2][64];
  __shared__ int flags[3];        // w0_done, w1_done, w2_done

  if (threadIdx.x < 3) flags[threadIdx.x] = -1;
  if (wid == 0) h0ring[15][lane] = 0.f;  // h0(-1) = 0
  if (wid == 2) h1pp[0][lane] = 0.f;     // h1(-1) = 0
  __syncthreads();

  volatile int* w0d = &flags[0];
  volatile int* w1d = &flags[1];
  volatile int* w2d = &flags[2];

  if (wid == 0) {
    // ---- layer-0 recurrence ----
    v2f wr2[32], wz2[32], wn2[32];
    loadw2(w_hh0 + (size_t)lane * 64,        wr2);
    loadw2(w_hh0 + (size_t)(64 + lane) * 64, wz2);
    loadw2(w_hh0 + (size_t)(128 + lane) * 64, wn2);
    float br = b_hh0[lane], bz = b_hh0[64 + lane], bn = b_hh0[128 + lane];
    float hv = 0.f;
    const float* xwb = xw0 + (size_t)b * TT * 192;
    float xr0 = xwb[      lane], xz0 = xwb[ 64 + lane], xn0 = xwb[128 + lane];
    float xr1 = xwb[192 + lane], xz1 = xwb[256 + lane], xn1 = xwb[320 + lane];
    float xr2 = xwb[384 + lane], xz2 = xwb[448 + lane], xn2 = xwb[512 + lane];
    float xr3 = xwb[576 + lane], xz3 = xwb[640 + lane], xn3 = xwb[704 + lane];

    auto gstep = [&](int s, float xr, float xz, float xn) {
      const float4* hp4 = (const float4*)h0ring[(s + 15) & 15];   // h0(s-1)
      v2f ar; ar.x = br; ar.y = 0.f;
      v2f az; az.x = bz; az.y = 0.f;
      v2f an; an.x = bn; an.y = 0.f;
      #pragma unroll
      for (int i = 0; i < 16; ++i) {
        float4 h4 = hp4[i];
        v2f hlo; hlo.x = h4.x; hlo.y = h4.y;
        v2f hhi; hhi.x = h4.z; hhi.y = h4.w;
        ar += wr2[2*i] * hlo; ar += wr2[2*i+1] * hhi;
        az += wz2[2*i] * hlo; az += wz2[2*i+1] * hhi;
        an += wn2[2*i] * hlo; an += wn2[2*i+1] * hhi;
      }
      float r = sigm(xr + (ar.x + ar.y));
      float z = sigm(xz + (az.x + az.y));
      float n = tanh_f(xn + r * (an.x + an.y));
      hv = (1.f - z) * n + z * hv;
      h0ring[s & 15][lane] = hv;
    };
    auto pf = [&](int s, float& a, float& bb_, float& c) {
      const float* xp = xwb + (size_t)s * 192;
      a = xp[lane]; bb_ = xp[64 + lane]; c = xp[128 + lane];
    };

    for (int s0 = 0; s0 < TT; s0 += 4) {
      if (s0 >= 16) spinwait(w1d, s0 - 13);   // slot reuse vs wave1 (4 groups back)
      bool dopf = (s0 < TT - 4);
      gstep(s0 + 0, xr0, xz0, xn0); if (dopf) pf(s0 + 4, xr0, xz0, xn0);
      gstep(s0 + 1, xr1, xz1, xn1); if (dopf) pf(s0 + 5, xr1, xz1, xn1);
      gstep(s0 + 2, xr2, xz2, xn2); if (dopf) pf(s0 + 6, xr2, xz2, xn2);
      gstep(s0 + 3, xr3, xz3, xn3); if (dopf) pf(s0 + 7, xr3, xz3, xn3);
      asm volatile("" ::: "memory");
      if (lane == 0) *w0d = s0 + 3;
    }
  } else if (wid == 1) {
    // ---- xw1(t) = W_ih1 . h0(t) + b_ih1 ----
    v2f wr2[32], wz2[32], wn2[32];
    loadw2(w_ih1 + (size_t)lane * 64,        wr2);
    loadw2(w_ih1 + (size_t)(64 + lane) * 64, wz2);
    loadw2(w_ih1 + (size_t)(128 + lane) * 64, wn2);
    float br = b_ih1[lane], bz = b_ih1[64 + lane], bn = b_ih1[128 + lane];

    for (int t0 = 0; t0 < TT; t0 += 4) {
      spinwait(w0d, t0 + 3);                   // h0(t0..t0+3) ready
      if (t0 >= 16) spinwait(w2d, t0 - 13);    // slot reuse vs wave2 (4 groups back)
      #pragma unroll
      for (int k = 0; k < 4; ++k) {
        int t = t0 + k;
        const float4* hp4 = (const float4*)h0ring[t & 15];
        v2f ar; ar.x = br; ar.y = 0.f;
        v2f az; az.x = bz; az.y = 0.f;
        v2f an; an.x = bn; an.y = 0.f;
        #pragma unroll
        for (int i = 0; i < 16; ++i) {
          float4 h4 = hp4[i];
          v2f hlo; hlo.x = h4.x; hlo.y = h4.y;
          v2f hhi; hhi.x = h4.z; hhi.y = h4.w;
          ar += wr2[2*i] * hlo; ar += wr2[2*i+1] * hhi;
          az += wz2[2*i] * hlo; az += wz2[2*i+1] * hhi;
          an += wn2[2*i] * hlo; an += wn2[2*i+1] * hhi;
        }
        xwring[t & 15][lane]       = ar.x + ar.y;
        xwring[t & 15][64 + lane]  = az.x + az.y;
        xwring[t & 15][128 + lane] = an.x + an.y;
      }
      asm volatile("" ::: "memory");
      if (lane == 0) *w1d = t0 + 3;
    }
  } else {
    // ---- layer-1 recurrence ----
    v2f wr2[32], wz2[32], wn2[32];
    loadw2(w_hh1 + (size_t)lane * 64,        wr2);
    loadw2(w_hh1 + (size_t)(64 + lane) * 64, wz2);
    loadw2(w_hh1 + (size_t)(128 + lane) * 64, wn2);
    float br = b_hh1[lane], bz = b_hh1[64 + lane], bn = b_hh1[128 + lane];
    float hv = 0.f;
    float* houtb = g1out + (size_t)b * TT * 64 + lane;

    for (int t0 = 0; t0 < TT; t0 += 4) {
      spinwait(w1d, t0 + 3);                   // xw1(t0..t0+3) ready
      #pragma unroll
      for (int k = 0; k < 4; ++k) {
        int t = t0 + k;
        float xr = xwring[t & 15][lane];
        float xz = xwring[t & 15][64 + lane];
        float xn = xwring[t & 15][128 + lane];
        const float4* hp4 = (const float4*)h1pp[t & 1];
        v2f ar; ar.x = br; ar.y = 0.f;
        v2f az; az.x = bz; az.y = 0.f;
        v2f an; an.x = bn; an.y = 0.f;
        #pragma unroll
        for (int i = 0; i < 16; ++i) {
          float4 h4 = hp4[i];
          v2f hlo; hlo.x = h4.x; hlo.y = h4.y;
          v2f hhi; hhi.x = h4.z; hhi.y = h4.w;
          ar += wr2[2*i] * hlo; ar += wr2[2*i+1] * hhi;
          az += wz2[2*i] * hlo; az += wz2[2*i+1] * hhi;
          an += wn2[2*i] * hlo; an += wn2[2*i+1] * hhi;
        }
        float r = sigm(xr + (ar.x + ar.y));
        float z = sigm(xz + (az.x + az.y));
        float n = tanh_f(xn + r * (an.x + an.y));
        hv = (1.f - z) * n + z * hv;
        h1pp[(t + 1) & 1][lane] = hv;
        houtb[(size_t)t * 64] = hv;            // fire-and-forget
      }
      asm volatile("" ::: "memory");
      if (lane == 0) *w2d = t0 + 3;
    }
  }
}

// ---------------- MHA1 qkv projection (K=64, G=192, 8x g-blocked) -> head-major f32 ----------------
extern "C" __global__ void __launch_bounds__(256)
k_qkv(const float* g1, const float* in_w1, const float* in_b1,
      float* q1, float* k1, float* v1) {
  int b  = blockIdx.x >> 4;
  int t0 = (blockIdx.x & 15) << 6;
  int tid = threadIdx.x;
  __shared__ float al[64 * 65];
  const float* act = g1 + ((size_t)b * TT + t0) * 64;
  for (int i = tid; i < 64 * 64; i += 256) {
    int r = i >> 6, c = i & 63;
    al[r * 65 + c] = act[r * 64 + c];
  }
  __syncthreads();
  int r = tid & 63, gq = tid >> 6;
  const float* ar = &al[r * 65];
  for (int g0 = gq * 8; g0 < 192; g0 += 32) {
    float acc[8];
    #pragma unroll
    for (int j = 0; j < 8; ++j) acc[j] = in_b1[g0 + j];
    #pragma unroll
    for (int c = 0; c < 64; ++c) {
      float a = ar[c];
      #pragma unroll
      for (int j = 0; j < 8; ++j) acc[j] += a * in_w1[(size_t)(g0 + j) * 64 + c];
    }
    int p = g0 / 64;            // 0=q 1=k 2=v (8-chunks never cross a 64-boundary)
    float* outp = (p == 0) ? q1 : ((p == 1) ? k1 : v1);
    #pragma unroll
    for (int j = 0; j < 8; ++j) {
      int rem = (g0 - p * 64) + j;
      int hd = rem >> 5, d = rem & 31;
      outp[(((size_t)b * 2 + hd) * TT + t0 + r) * 32 + d] = acc[j];
    }
  }
}

// ---------------- MHA1 flash attention, key-split S=2, TWO q-rows per thread ----------------
extern "C" __global__ void __launch_bounds__(256, 2)
k_attn(const float* q1, const float* k1, const float* v1, float* po, float* ml) {
  int gid = blockIdx.x;          // 512 blocks: b(6)|h(1)|seg(1)|qb(1)
  int b   = gid >> 3;
  int h   = (gid >> 2) & 1;
  int seg = (gid >> 1) & 1;
  int qb  = gid & 1;
  int tid = threadIdx.x;
  int tq0 = qb * 512 + tid;      // rows tq0 and tq0+256
  __shared__ __align__(16) float Kt[64 * 32];
  __shared__ __align__(16) float Vt[64 * 32];
  float qa[32], qc[32], oa[32], oc[32];
  const float* qp0 = q1 + (((size_t)b * 2 + h) * TT + tq0) * 32;
  const float* qp1 = qp0 + 256 * 32;
  #pragma unroll
  for (int i = 0; i < 8; ++i) {
    float4 v0 = ((const float4*)qp0)[i];
    float4 v1r = ((const float4*)qp1)[i];
    qa[4*i] = v0.x; qa[4*i+1] = v0.y; qa[4*i+2] = v0.z; qa[4*i+3] = v0.w;
    qc[4*i] = v1r.x; qc[4*i+1] = v1r.y; qc[4*i+2] = v1r.z; qc[4*i+3] = v1r.w;
  }
  #pragma unroll
  for (int i = 0; i < 32; ++i) { oa[i] = 0.f; oc[i] = 0.f; }
  float m0 = -1e30f, l0 = 0.f, m1 = -1e30f, l1 = 0.f;
  const float scale = 0.17677669529663687f;   // 1/sqrt(32)
  const float4* kb = (const float4*)(k1 + ((size_t)b * 2 + h) * TT * 32);
  const float4* vb = (const float4*)(v1 + ((size_t)b * 2 + h) * TT * 32);
  int k0 = seg << 9;                           // seg*512
  for (int kt = k0; kt < k0 + 512; kt += 64) {
    __syncthreads();
    ((float4*)Kt)[tid]       = kb[kt * 8 + tid];
    ((float4*)Kt)[tid + 256] = kb[kt * 8 + tid + 256];
    ((float4*)Vt)[tid]       = vb[kt * 8 + tid];
    ((float4*)Vt)[tid + 256] = vb[kt * 8 + tid + 256];
    __syncthreads();
    #pragma unroll 1
    for (int c0 = 0; c0 < 64; c0 += 8) {
      float sv0[8], sv1[8];
      #pragma unroll
      for (int j = 0; j < 8; ++j) {
        const float4* kr = (const float4*)&Kt[(c0 + j) * 32];
        float a0 = 0, a1 = 0, c0a = 0, c1a = 0;
        #pragma unroll
        for (int i = 0; i < 8; ++i) {
          float4 kv = kr[i];                       // one broadcast read, 2 q-rows
          a0 += qa[4*i]   * kv.x; a1 += qa[4*i+1] * kv.y;
          a0 += qa[4*i+2] * kv.z; a1 += qa[4*i+3] * kv.w;
          c0a += qc[4*i]   * kv.x; c1a += qc[4*i+1] * kv.y;
          c0a += qc[4*i+2] * kv.z; c1a += qc[4*i+3] * kv.w;
        }
        sv0[j] = (a0 + a1) * scale;
        sv1[j] = (c0a + c1a) * scale;
      }
      float cm0 = sv0[0], cm1 = sv1[0];
      #pragma unroll
      for (int j = 1; j < 8; ++j) { cm0 = fmaxf(cm0, sv0[j]); cm1 = fmaxf(cm1, sv1[j]); }
      float mn0 = fmaxf(m0, cm0), mn1 = fmaxf(m1, cm1);
      float al0 = __expf(m0 - mn0), al1 = __expf(m1 - mn1);
      float ps0 = 0.f, ps1 = 0.f;
      #pragma unroll
      for (int j = 0; j < 8; ++j) {
        sv0[j] = __expf(sv0[j] - mn0); ps0 += sv0[j];
        sv1[j] = __expf(sv1[j] - mn1); ps1 += sv1[j];
      }
      l0 = l0 * al0 + ps0; m0 = mn0;
      l1 = l1 * al1 + ps1; m1 = mn1;
      #pragma unroll
      for (int i = 0; i < 8; ++i) {
        float4 A, C;
        A.x = oa[4*i] * al0; A.y = oa[4*i+1] * al0; A.z = oa[4*i+2] * al0; A.w = oa[4*i+3] * al0;
        C.x = oc[4*i] * al1; C.y = oc[4*i+1] * al1; C.z = oc[4*i+2] * al1; C.w = oc[4*i+3] * al1;
        #pragma unroll
        for (int j = 0; j < 8; ++j) {
          float4 vv = *(const float4*)&Vt[(c0 + j) * 32 + 4 * i];   // shared read
          A.x += sv0[j] * vv.x; A.y += sv0[j] * vv.y; A.z += sv0[j] * vv.z; A.w += sv0[j] * vv.w;
          C.x += sv1[j] * vv.x; C.y += sv1[j] * vv.y; C.z += sv1[j] * vv.z; C.w += sv1[j] * vv.w;
        }
        oa[4*i] = A.x; oa[4*i+1] = A.y; oa[4*i+2] = A.z; oa[4*i+3] = A.w;
        oc[4*i] = C.x; oc[4*i+1] = C.y; oc[4*i+2] = C.z; oc[4*i+3] = C.w;
      }
    }
  }
  size_t rb0 = (((size_t)(b * 2 + h)) * 2 + seg) * TT + tq0;
  size_t rb1 = rb0 + 256;
  float* op0 = po + rb0 * 32;
  float* op1 = po + rb1 * 32;
  #pragma unroll
  for (int i = 0; i < 8; ++i) {
    float4 s0; s0.x = oa[4*i]; s0.y = oa[4*i+1]; s0.z = oa[4*i+2]; s0.w = oa[4*i+3];
    float4 s1; s1.x = oc[4*i]; s1.y = oc[4*i+1]; s1.z = oc[4*i+2]; s1.w = oc[4*i+3];
    ((float4*)op0)[i] = s0;
    ((float4*)op1)[i] = s1;
  }
  ml[rb0 * 2 + 0] = m0; ml[rb0 * 2 + 1] = l0;
  ml[rb1 * 2 + 0] = m1; ml[rb1 * 2 + 1] = l1;
}

// ---------------- combine the two key-segments -> attnO [b][t][64] ----------------
extern "C" __global__ void __launch_bounds__(256)
k_attn_comb(const float* po, const float* ml, float* attnO) {
  int row = blockIdx.x * 256 + threadIdx.x;   // 0 .. 64*2*1024-1
  int bh = row >> 10;
  int t  = row & 1023;
  int b = bh >> 1, h = bh & 1;
  size_t r0 = ((size_t)bh * 2 + 0) * TT + t;
  size_t r1 = ((size_t)bh * 2 + 1) * TT + t;
  float m0 = ml[r0 * 2], l0 = ml[r0 * 2 + 1];
  float m1 = ml[r1 * 2], l1 = ml[r1 * 2 + 1];
  float m = fmaxf(m0, m1);
  float w0 = __expf(m0 - m), w1 = __expf(m1 - m);
  float inv = 1.f / (w0 * l0 + w1 * l1);
  w0 *= inv; w1 *= inv;
  const float4* p0 = (const float4*)(po + r0 * 32);
  const float4* p1 = (const float4*)(po + r1 * 32);
  float* op = attnO + ((size_t)b * TT + t) * 64 + h * 32;
  #pragma unroll
  for (int i = 0; i < 8; ++i) {
    float4 a = p0[i], c = p1[i], r;
    r.x = a.x * w0 + c.x * w1; r.y = a.y * w0 + c.y * w1;
    r.z = a.z * w0 + c.z * w1; r.w = a.w * w0 + c.w * w1;
    ((float4*)op)[i] = r;
  }
}

// ---------------- MHA1 output projection (K=64, G=64, 8x g-blocked) ----------------
extern "C" __global__ void __launch_bounds__(256)
k_oproj(const float* attnO, const float* out_w1, const float* out_b1, float* a1) {
  int b  = blockIdx.x >> 4;
  int t0 = (blockIdx.x & 15) << 6;
  __shared__ float al[64 * 65];
  gemm64b(attnO + ((size_t)b * TT + t0) * 64, out_w1, out_b1, al, 64, threadIdx.x,
          a1, 64, ((size_t)b * TT + t0) * 64);
}

// ---------------- MHA2: scores s2 + values v2 (8x d-blocked act-read reuse) ----------------
extern "C" __global__ void __launch_bounds__(256)
k_mha2kv(const float* a1, const float* in_w2, const float* in_b2,
         float* s2, float* v2) {
  int b  = blockIdx.x >> 4;
  int t0 = (blockIdx.x & 15) << 6;
  int tid = threadIdx.x;
  __shared__ float a1r[64 * 65];
  __shared__ float q2s[64];
  __shared__ float alast[64];
  if (tid < 64) alast[tid] = a1[((size_t)b * TT + (TT - 1)) * 64 + tid];
  for (int i = tid; i < 4096; i += 256) {
    int r = i >> 6, e = i & 63;
    a1r[r * 65 + e] = a1[((size_t)b * TT + t0 + r) * 64 + e];
  }
  __syncthreads();
  if (tid < 64) {
    float acc = in_b2[tid];
    const float* wr = in_w2 + (size_t)tid * 64;
    #pragma unroll
    for (int e = 0; e < 64; ++e) acc += alast[e] * wr[e];
    q2s[tid] = acc;
  }
  __syncthreads();
  int tt = tid & 63;
  int role = tid >> 6;
  const float* ar = &a1r[tt * 65];
  const float scale = 0.17677669529663687f;
  if (role < 2) {
    // head `role`: score for key position t0+tt; 8 k-dims share each act read
    float s = 0.f;
    for (int d0 = 0; d0 < 32; d0 += 8) {
      int row0 = 64 + role * 32 + d0;          // k rows 64..127 (wave-uniform)
      float acc[8];
      #pragma unroll
      for (int j = 0; j < 8; ++j) acc[j] = in_b2[row0 + j];
      #pragma unroll
      for (int e = 0; e < 64; ++e) {
        float a = ar[e];
        #pragma unroll
        for (int j = 0; j < 8; ++j) acc[j] += a * in_w2[(size_t)(row0 + j) * 64 + e];
      }
      #pragma unroll
      for (int j = 0; j < 8; ++j) s += q2s[row0 - 64 + j] * acc[j];
    }
    s2[((size_t)b * 2 + role) * TT + t0 + tt] = s * scale;
  } else {
    int half = role - 2;                        // v dims [half*32, half*32+32)
    for (int d0 = 0; d0 < 32; d0 += 8) {
      int row0 = 128 + half * 32 + d0;          // v rows 128..191 (wave-uniform)
      float acc[8];
      #pragma unroll
      for (int j = 0; j < 8; ++j) acc[j] = in_b2[row0 + j];
      #pragma unroll
      for (int e = 0; e < 64; ++e) {
        float a = ar[e];
        #pragma unroll
        for (int j = 0; j < 8; ++j) acc[j] += a * in_w2[(size_t)(row0 + j) * 64 + e];
      }
      #pragma unroll
      for (int j = 0; j < 8; ++j)
        v2[((size_t)b * TT + t0 + tt) * 64 + half * 32 + d0 + j] = acc[j];
    }
  }
}

// ---------------- MHA2 softmax+PV, out-proj, final MLP ----------------
extern "C" __global__ void __launch_bounds__(256)
k_final(const float* s2, const float* v2,
        const float* out_w2, const float* out_b2,
        const float* w_l, const float* b_l,
        const float* w_l1, const float* b_l1,
        float* out) {
  int b = blockIdx.x;
  int tid = threadIdx.x;
  __shared__ float sm[2 * 1024];
  __shared__ float red[8];
  __shared__ float invl[2];
  __shared__ float opart[4 * 64];
  __shared__ float of[64];
  __shared__ float a2[64];
  __shared__ float hbuf[32];
  __shared__ int bad;
  if (tid == 0) bad = 0;
  for (int i = tid; i < 2048; i += 256) sm[i] = s2[(size_t)b * 2 * TT + i];
  __syncthreads();
  int lane = tid & 63;
  int wid = tid >> 6;
  for (int hh = 0; hh < 2; ++hh) {
    float mx = -1e30f;
    for (int i = tid; i < 1024; i += 256) mx = fmaxf(mx, sm[hh * 1024 + i]);
    #pragma unroll
    for (int off = 32; off > 0; off >>= 1) mx = fmaxf(mx, __shfl_down(mx, off));
    if (lane == 0) red[wid] = mx;
    __syncthreads();
    if (tid == 0) red[4] = fmaxf(fmaxf(red[0], red[1]), fmaxf(red[2], red[3]));
    __syncthreads();
    mx = red[4];
    float s = 0.f;
    for (int i = tid; i < 1024; i += 256) {
      float e = __expf(sm[hh * 1024 + i] - mx);
      sm[hh * 1024 + i] = e;
      s += e;
    }
    #pragma unroll
    for (int off = 32; off > 0; off >>= 1) s += __shfl_down(s, off);
    if (lane == 0) red[wid] = s;
    __syncthreads();
    if (tid == 0) invl[hh] = 1.f / (red[0] + red[1] + red[2] + red[3]);
    __syncthreads();
  }
  {
    int dp = tid & 63;
    int part = tid >> 6;
    int hh = dp >> 5;
    float acc = 0.f;
    for (int t = part * 256; t < part * 256 + 256; ++t)
      acc += sm[hh * 1024 + t] * v2[((size_t)b * TT + t) * 64 + dp];
    opart[part * 64 + dp] = acc;
  }
  __syncthreads();
  if (tid < 64) {
    float o = (opart[tid] + opart[64 + tid] + opart[128 + tid] + opart[192 + tid]) * invl[tid >> 5];
    of[tid] = o;
    if (!finitef(o)) bad = 1;
  }
  __syncthreads();
  if (tid < 64) {
    float acc = out_b2[tid];
    const float* wr = out_w2 + (size_t)tid * 64;
    #pragma unroll
    for (int d = 0; d < 64; ++d) acc += of[d] * wr[d];
    a2[tid] = acc;
  }
  __syncthreads();
  if (tid < 32) {
    float acc = b_l[tid];
    const float* wr = w_l + (size_t)tid * 64;
    #pragma unroll
    for (int e = 0; e < 64; ++e) acc += a2[e] * wr[e];
    hbuf[tid] = fmaxf(acc, 0.f);
  }
  __syncthreads();
  if (tid == 0) {
    float acc = b_l1[0];
    #pragma unroll
    for (int j = 0; j < 32; ++j) acc += hbuf[j] * w_l1[j];
    out[b] = bad ? 777.0f : acc;
  }
}

extern "C" void kernel_launch(void* const* d_in, const int* in_sizes, int n_in,
                              void* d_out, int out_size, void* d_ws, size_t ws_size,
                              hipStream_t stream) {
  const int*   atom_idx  = (const int*)d_in[0];
  const float* bond_dist = (const float*)d_in[1];
  const float* emb       = (const float*)d_in[2];
  const float* w_ih0     = (const float*)d_in[3];
  const float* w_hh0     = (const float*)d_in[4];
  const float* b_ih0     = (const float*)d_in[5];
  const float* b_hh0     = (const float*)d_in[6];
  const float* w_ih1     = (const float*)d_in[7];
  const float* w_hh1     = (const float*)d_in[8];
  const float* b_ih1     = (const float*)d_in[9];
  const float* b_hh1     = (const float*)d_in[10];
  const float* in_w1     = (const float*)d_in[11];
  const float* in_b1     = (const float*)d_in[12];
  const float* out_w1    = (const float*)d_in[13];
  const float* out_b1    = (const float*)d_in[14];
  const float* in_w2     = (const float*)d_in[15];
  const float* in_b2     = (const float*)d_in[16];
  const float* out_w2    = (const float*)d_in[17];
  const float* out_b2    = (const float*)d_in[18];
  const float* w_l       = (const float*)d_in[19];
  const float* b_l       = (const float*)d_in[20];
  const float* w_l1      = (const float*)d_in[21];
  const float* b_l1      = (const float*)d_in[22];

  // Arena plan (84,410,368 B total), all f32:
  //   X @ 0        (50.3 MB): xw0 -> {q,k,v | po} -> v2
  //   A @ 50331648 (16.8 MB): attnO
  //   B @ 67108864 (16.8 MB): g1 -> ml (2MB, during attn) -> a1
  //   D @ 83886080 (0.5 MB):  s2
  char* ws = (char*)d_ws;
  float* X  = (float*)(ws);
  float* A  = (float*)(ws + 50331648);
  float* Bq = (float*)(ws + 67108864);
  float* D  = (float*)(ws + 83886080);
  float* q1 = X;
  float* k1 = X + 4194304;
  float* v1 = X + 8388608;
  float* po = (float*)(ws + 16777216);   // [bh][seg][t][32] = 33,554,432 B, ends exactly at A
  float* ml = Bq;                        // [bh][seg][t][2]  = 2 MB, dead before oproj writes a1

  k_xw0      <<<dim3(1024), dim3(256), 0, stream>>>(atom_idx, bond_dist, emb, w_ih0, b_ih0, X);
  k_grufused <<<dim3(64),   dim3(192), 0, stream>>>(X, w_hh0, b_hh0, w_ih1, b_ih1, w_hh1, b_hh1, Bq);
  k_qkv      <<<dim3(1024), dim3(256), 0, stream>>>(Bq, in_w1, in_b1, q1, k1, v1);
  k_attn     <<<dim3(512),  dim3(256), 0, stream>>>(q1, k1, v1, po, ml);
  k_attn_comb<<<dim3(512),  dim3(256), 0, stream>>>(po, ml, A);
  k_oproj    <<<dim3(1024), dim3(256), 0, stream>>>(A, out_w1, out_b1, Bq);
  k_mha2kv   <<<dim3(1024), dim3(256), 0, stream>>>(Bq, in_w2, in_b2, D, X);
  k_final    <<<dim3(64),   dim3(256), 0, stream>>>(D, X, out_w2, out_b2, w_l, b_l, w_l1, b_l1, (float*)d_out);
}

// Round 11
// 1301.386 us; speedup vs baseline: 1.5787x; 1.0311x over previous
//
#include <hip/hip_runtime.h>

typedef unsigned int uint_t;
typedef float v2f __attribute__((ext_vector_type(2)));

#define BB 64
#define TT 1024

__device__ __forceinline__ float sigm(float x) { return 1.f / (1.f + __expf(-x)); }
__device__ __forceinline__ float tanh_f(float x) { float e = __expf(2.f * x); return 1.f - 2.f / (e + 1.f); }
__device__ __forceinline__ int finitef(float x) { return (x == x) && (fabsf(x) < 1e30f); }

// Bounded wait on an LDS flag (monotone step counter) with s_sleep backoff.
// Cap => sync bug gives wrong answer, not hang.
__device__ __forceinline__ void spinwait(volatile int* f, int v) {
  if (*f >= v) { asm volatile("" ::: "memory"); return; }
  int it = 0;
  while (*f < v && it < (1 << 15)) { __builtin_amdgcn_s_sleep(1); ++it; }
  asm volatile("" ::: "memory");
}

// x feature j of token (b,t): [e_i(0..9) | e_j(10..19) | rbf(20..29)]
__device__ __forceinline__ float feat(int b, int t, int j,
                                      const int* atom_idx, const float* bond_dist,
                                      const float* emb) {
  int ii = atom_idx[(b * TT + t) * 2 + 0];
  if (j < 10) {
    return ii ? emb[ii * 10 + j] : 0.f;
  } else if (j < 20) {
    int jj = atom_idx[(b * TT + t) * 2 + 1];
    return jj ? emb[jj * 10 + (j - 10)] : 0.f;
  } else {
    float d = bond_dist[b * TT + t];
    float c = (float)(j - 19);
    float df = c - d;
    return ii ? __expf(-df * df) : 0.f;
  }
}

// ---------------- xw0 = x @ w_ih0.T + b_ih0  (K=30, G=192, 8x g-blocked) ----------------
extern "C" __global__ void __launch_bounds__(256)
k_xw0(const int* atom_idx, const float* bond_dist, const float* emb,
      const float* w_ih0, const float* b_ih0, float* xw0) {
  int b  = blockIdx.x >> 4;
  int t0 = (blockIdx.x & 15) << 6;
  int tid = threadIdx.x;
  __shared__ float xt[64 * 31];
  for (int i = tid; i < 64 * 30; i += 256) {
    int r = i / 30, j = i % 30;
    xt[r * 31 + j] = feat(b, t0 + r, j, atom_idx, bond_dist, emb);
  }
  __syncthreads();
  int r = tid & 63, gq = tid >> 6;
  const float* ar = &xt[r * 31];
  for (int g0 = gq * 8; g0 < 192; g0 += 32) {
    float acc[8];
    #pragma unroll
    for (int j = 0; j < 8; ++j) acc[j] = b_ih0[g0 + j];
    #pragma unroll
    for (int c = 0; c < 30; ++c) {
      float a = ar[c];
      #pragma unroll
      for (int j = 0; j < 8; ++j) acc[j] += a * w_ih0[(g0 + j) * 30 + c];
    }
    #pragma unroll
    for (int j = 0; j < 8; ++j)
      xw0[((size_t)b * TT + t0 + r) * 192 + g0 + j] = acc[j];
  }
}

// ---------------- (64 rows) x (G x 64) GEMM, 8x g-blocked ----------------
__device__ __forceinline__ void gemm64b(const float* __restrict__ act_g,
                                        const float* __restrict__ w,
                                        const float* __restrict__ bias,
                                        float* al,
                                        int G, int tid,
                                        float* out, int out_rstride, size_t out_base) {
  for (int i = tid; i < 64 * 64; i += 256) {
    int r = i >> 6, c = i & 63;
    al[r * 65 + c] = act_g[r * 64 + c];
  }
  __syncthreads();
  int r = tid & 63, gq = tid >> 6;
  const float* ar = &al[r * 65];
  for (int g0 = gq * 8; g0 < G; g0 += 32) {
    float acc[8];
    #pragma unroll
    for (int j = 0; j < 8; ++j) acc[j] = bias[g0 + j];
    #pragma unroll
    for (int c = 0; c < 64; ++c) {
      float a = ar[c];
      #pragma unroll
      for (int j = 0; j < 8; ++j) acc[j] += a * w[(size_t)(g0 + j) * 64 + c];
    }
    #pragma unroll
    for (int j = 0; j < 8; ++j)
      out[out_base + (size_t)r * out_rstride + g0 + j] = acc[j];
  }
}

// Load a 64-wide weight row into 32 packed v2f registers.
__device__ __forceinline__ void loadw2(const float* p, v2f* w2) {
  const float4* p4 = (const float4*)p;
  #pragma unroll
  for (int i = 0; i < 16; ++i) {
    float4 a = p4[i];
    v2f lo; lo.x = a.x; lo.y = a.y;
    v2f hi; hi.x = a.z; hi.y = a.w;
    w2[2 * i] = lo; w2[2 * i + 1] = hi;
  }
}

// ---------------- fused GRU0 -> xw1 -> GRU1 : 3-stage wave pipeline (R8-proven, 604us) ----------------
// R9 lesson: merging xw1 into wave0 needs ~420 VGPR; compiler caps at 248 and spills
// the weight arrays into the serial loop (604->1344us). 3-wave split (124 VGPR, fits):
// wave0 GRU0, wave1 xw1, wave2 GRU1; depth-16 rings; packed v2f math.
extern "C" __global__ void __launch_bounds__(192, 1)
k_grufused(const float* xw0, const float* w_hh0, const float* b_hh0,
           const float* w_ih1, const float* b_ih1,
           const float* w_hh1, const float* b_hh1, float* g1out) {
  int b    = blockIdx.x;
  int lane = threadIdx.x & 63;
  int wid  = threadIdx.x >> 6;
  __shared__ __align__(16) float h0ring[16][64];
  __shared__ __align__(16) float xwring[16][192];
  __shared__ __align__(16) float h1pp[2][64];
  __shared__ int flags[3];        // w0_done, w1_done, w2_done

  if (threadIdx.x < 3) flags[threadIdx.x] = -1;
  if (wid == 0) h0ring[15][lane] = 0.f;  // h0(-1) = 0
  if (wid == 2) h1pp[0][lane] = 0.f;     // h1(-1) = 0
  __syncthreads();

  volatile int* w0d = &flags[0];
  volatile int* w1d = &flags[1];
  volatile int* w2d = &flags[2];

  if (wid == 0) {
    // ---- layer-0 recurrence ----
    v2f wr2[32], wz2[32], wn2[32];
    loadw2(w_hh0 + (size_t)lane * 64,        wr2);
    loadw2(w_hh0 + (size_t)(64 + lane) * 64, wz2);
    loadw2(w_hh0 + (size_t)(128 + lane) * 64, wn2);
    float br = b_hh0[lane], bz = b_hh0[64 + lane], bn = b_hh0[128 + lane];
    float hv = 0.f;
    const float* xwb = xw0 + (size_t)b * TT * 192;
    float xr0 = xwb[      lane], xz0 = xwb[ 64 + lane], xn0 = xwb[128 + lane];
    float xr1 = xwb[192 + lane], xz1 = xwb[256 + lane], xn1 = xwb[320 + lane];
    float xr2 = xwb[384 + lane], xz2 = xwb[448 + lane], xn2 = xwb[512 + lane];
    float xr3 = xwb[576 + lane], xz3 = xwb[640 + lane], xn3 = xwb[704 + lane];

    auto gstep = [&](int s, float xr, float xz, float xn) {
      const float4* hp4 = (const float4*)h0ring[(s + 15) & 15];   // h0(s-1)
      v2f ar; ar.x = br; ar.y = 0.f;
      v2f az; az.x = bz; az.y = 0.f;
      v2f an; an.x = bn; an.y = 0.f;
      #pragma unroll
      for (int i = 0; i < 16; ++i) {
        float4 h4 = hp4[i];
        v2f hlo; hlo.x = h4.x; hlo.y = h4.y;
        v2f hhi; hhi.x = h4.z; hhi.y = h4.w;
        ar += wr2[2*i] * hlo; ar += wr2[2*i+1] * hhi;
        az += wz2[2*i] * hlo; az += wz2[2*i+1] * hhi;
        an += wn2[2*i] * hlo; an += wn2[2*i+1] * hhi;
      }
      float r = sigm(xr + (ar.x + ar.y));
      float z = sigm(xz + (az.x + az.y));
      float n = tanh_f(xn + r * (an.x + an.y));
      hv = (1.f - z) * n + z * hv;
      h0ring[s & 15][lane] = hv;
    };
    auto pf = [&](int s, float& a, float& bb_, float& c) {
      const float* xp = xwb + (size_t)s * 192;
      a = xp[lane]; bb_ = xp[64 + lane]; c = xp[128 + lane];
    };

    for (int s0 = 0; s0 < TT; s0 += 4) {
      if (s0 >= 16) spinwait(w1d, s0 - 13);   // slot reuse vs wave1 (4 groups back)
      bool dopf = (s0 < TT - 4);
      gstep(s0 + 0, xr0, xz0, xn0); if (dopf) pf(s0 + 4, xr0, xz0, xn0);
      gstep(s0 + 1, xr1, xz1, xn1); if (dopf) pf(s0 + 5, xr1, xz1, xn1);
      gstep(s0 + 2, xr2, xz2, xn2); if (dopf) pf(s0 + 6, xr2, xz2, xn2);
      gstep(s0 + 3, xr3, xz3, xn3); if (dopf) pf(s0 + 7, xr3, xz3, xn3);
      asm volatile("" ::: "memory");
      if (lane == 0) *w0d = s0 + 3;
    }
  } else if (wid == 1) {
    // ---- xw1(t) = W_ih1 . h0(t) + b_ih1 ----
    v2f wr2[32], wz2[32], wn2[32];
    loadw2(w_ih1 + (size_t)lane * 64,        wr2);
    loadw2(w_ih1 + (size_t)(64 + lane) * 64, wz2);
    loadw2(w_ih1 + (size_t)(128 + lane) * 64, wn2);
    float br = b_ih1[lane], bz = b_ih1[64 + lane], bn = b_ih1[128 + lane];

    for (int t0 = 0; t0 < TT; t0 += 4) {
      spinwait(w0d, t0 + 3);                   // h0(t0..t0+3) ready
      if (t0 >= 16) spinwait(w2d, t0 - 13);    // slot reuse vs wave2 (4 groups back)
      #pragma unroll
      for (int k = 0; k < 4; ++k) {
        int t = t0 + k;
        const float4* hp4 = (const float4*)h0ring[t & 15];
        v2f ar; ar.x = br; ar.y = 0.f;
        v2f az; az.x = bz; az.y = 0.f;
        v2f an; an.x = bn; an.y = 0.f;
        #pragma unroll
        for (int i = 0; i < 16; ++i) {
          float4 h4 = hp4[i];
          v2f hlo; hlo.x = h4.x; hlo.y = h4.y;
          v2f hhi; hhi.x = h4.z; hhi.y = h4.w;
          ar += wr2[2*i] * hlo; ar += wr2[2*i+1] * hhi;
          az += wz2[2*i] * hlo; az += wz2[2*i+1] * hhi;
          an += wn2[2*i] * hlo; an += wn2[2*i+1] * hhi;
        }
        xwring[t & 15][lane]       = ar.x + ar.y;
        xwring[t & 15][64 + lane]  = az.x + az.y;
        xwring[t & 15][128 + lane] = an.x + an.y;
      }
      asm volatile("" ::: "memory");
      if (lane == 0) *w1d = t0 + 3;
    }
  } else {
    // ---- layer-1 recurrence ----
    v2f wr2[32], wz2[32], wn2[32];
    loadw2(w_hh1 + (size_t)lane * 64,        wr2);
    loadw2(w_hh1 + (size_t)(64 + lane) * 64, wz2);
    loadw2(w_hh1 + (size_t)(128 + lane) * 64, wn2);
    float br = b_hh1[lane], bz = b_hh1[64 + lane], bn = b_hh1[128 + lane];
    float hv = 0.f;
    float* houtb = g1out + (size_t)b * TT * 64 + lane;

    for (int t0 = 0; t0 < TT; t0 += 4) {
      spinwait(w1d, t0 + 3);                   // xw1(t0..t0+3) ready
      #pragma unroll
      for (int k = 0; k < 4; ++k) {
        int t = t0 + k;
        float xr = xwring[t & 15][lane];
        float xz = xwring[t & 15][64 + lane];
        float xn = xwring[t & 15][128 + lane];
        const float4* hp4 = (const float4*)h1pp[t & 1];
        v2f ar; ar.x = br; ar.y = 0.f;
        v2f az; az.x = bz; az.y = 0.f;
        v2f an; an.x = bn; an.y = 0.f;
        #pragma unroll
        for (int i = 0; i < 16; ++i) {
          float4 h4 = hp4[i];
          v2f hlo; hlo.x = h4.x; hlo.y = h4.y;
          v2f hhi; hhi.x = h4.z; hhi.y = h4.w;
          ar += wr2[2*i] * hlo; ar += wr2[2*i+1] * hhi;
          az += wz2[2*i] * hlo; az += wz2[2*i+1] * hhi;
          an += wn2[2*i] * hlo; an += wn2[2*i+1] * hhi;
        }
        float r = sigm(xr + (ar.x + ar.y));
        float z = sigm(xz + (az.x + az.y));
        float n = tanh_f(xn + r * (an.x + an.y));
        hv = (1.f - z) * n + z * hv;
        h1pp[(t + 1) & 1][lane] = hv;
        houtb[(size_t)t * 64] = hv;            // fire-and-forget
      }
      asm volatile("" ::: "memory");
      if (lane == 0) *w2d = t0 + 3;
    }
  }
}

// ---------------- MHA1 qkv projection (K=64, G=192, 8x g-blocked) -> head-major f32 ----------------
extern "C" __global__ void __launch_bounds__(256)
k_qkv(const float* g1, const float* in_w1, const float* in_b1,
      float* q1, float* k1, float* v1) {
  int b  = blockIdx.x >> 4;
  int t0 = (blockIdx.x & 15) << 6;
  int tid = threadIdx.x;
  __shared__ float al[64 * 65];
  const float* act = g1 + ((size_t)b * TT + t0) * 64;
  for (int i = tid; i < 64 * 64; i += 256) {
    int r = i >> 6, c = i & 63;
    al[r * 65 + c] = act[r * 64 + c];
  }
  __syncthreads();
  int r = tid & 63, gq = tid >> 6;
  const float* ar = &al[r * 65];
  for (int g0 = gq * 8; g0 < 192; g0 += 32) {
    float acc[8];
    #pragma unroll
    for (int j = 0; j < 8; ++j) acc[j] = in_b1[g0 + j];
    #pragma unroll
    for (int c = 0; c < 64; ++c) {
      float a = ar[c];
      #pragma unroll
      for (int j = 0; j < 8; ++j) acc[j] += a * in_w1[(size_t)(g0 + j) * 64 + c];
    }
    int p = g0 / 64;            // 0=q 1=k 2=v (8-chunks never cross a 64-boundary)
    float* outp = (p == 0) ? q1 : ((p == 1) ? k1 : v1);
    #pragma unroll
    for (int j = 0; j < 8; ++j) {
      int rem = (g0 - p * 64) + j;
      int hd = rem >> 5, d = rem & 31;
      outp[(((size_t)b * 2 + hd) * TT + t0 + r) * 32 + d] = acc[j];
    }
  }
}

// ---------------- MHA1 flash attention, key-split S=2, 2 q-rows/thread, PACKED v2f ----------------
// R10 analysis: with 2 rows/thread the kernel is VALU-issue-bound (~65K scalar FMA/thread).
// Row-pair packs naturally into v2f: one v_pk_fma_f32 does both rows per K/V scalar.
extern "C" __global__ void __launch_bounds__(256, 2)
k_attn(const float* q1, const float* k1, const float* v1, float* po, float* ml) {
  int gid = blockIdx.x;          // 512 blocks: b(6)|h(1)|seg(1)|qb(1)
  int b   = gid >> 3;
  int h   = (gid >> 2) & 1;
  int seg = (gid >> 1) & 1;
  int qb  = gid & 1;
  int tid = threadIdx.x;
  int tq0 = qb * 512 + tid;      // rows tq0 and tq0+256
  __shared__ __align__(16) float Kt[64 * 32];
  __shared__ __align__(16) float Vt[64 * 32];
  v2f q2[32], o2[32];            // .x = row tq0, .y = row tq0+256
  const float* qp0 = q1 + (((size_t)b * 2 + h) * TT + tq0) * 32;
  const float* qp1 = qp0 + 256 * 32;
  #pragma unroll
  for (int i = 0; i < 8; ++i) {
    float4 v0 = ((const float4*)qp0)[i];
    float4 v1r = ((const float4*)qp1)[i];
    q2[4*i+0] = (v2f){v0.x, v1r.x};
    q2[4*i+1] = (v2f){v0.y, v1r.y};
    q2[4*i+2] = (v2f){v0.z, v1r.z};
    q2[4*i+3] = (v2f){v0.w, v1r.w};
  }
  #pragma unroll
  for (int i = 0; i < 32; ++i) o2[i] = (v2f){0.f, 0.f};
  float m0 = -1e30f, l0 = 0.f, m1 = -1e30f, l1 = 0.f;
  const float scale = 0.17677669529663687f;   // 1/sqrt(32)
  const float4* kb = (const float4*)(k1 + ((size_t)b * 2 + h) * TT * 32);
  const float4* vb = (const float4*)(v1 + ((size_t)b * 2 + h) * TT * 32);
  int k0 = seg << 9;                           // seg*512
  for (int kt = k0; kt < k0 + 512; kt += 64) {
    __syncthreads();
    ((float4*)Kt)[tid]       = kb[kt * 8 + tid];
    ((float4*)Kt)[tid + 256] = kb[kt * 8 + tid + 256];
    ((float4*)Vt)[tid]       = vb[kt * 8 + tid];
    ((float4*)Vt)[tid + 256] = vb[kt * 8 + tid + 256];
    __syncthreads();
    #pragma unroll 1
    for (int c0 = 0; c0 < 64; c0 += 8) {
      v2f sv2[8];
      #pragma unroll
      for (int j = 0; j < 8; ++j) {
        const float4* kr = (const float4*)&Kt[(c0 + j) * 32];
        v2f a0 = (v2f){0.f, 0.f}, a1 = (v2f){0.f, 0.f};
        #pragma unroll
        for (int i = 0; i < 8; ++i) {
          float4 kv = kr[i];                   // one broadcast read, both rows packed
          a0 += q2[4*i+0] * (v2f){kv.x, kv.x};
          a1 += q2[4*i+1] * (v2f){kv.y, kv.y};
          a0 += q2[4*i+2] * (v2f){kv.z, kv.z};
          a1 += q2[4*i+3] * (v2f){kv.w, kv.w};
        }
        v2f s = a0 + a1;
        sv2[j] = (v2f){s.x * scale, s.y * scale};
      }
      float cm0 = sv2[0].x, cm1 = sv2[0].y;
      #pragma unroll
      for (int j = 1; j < 8; ++j) { cm0 = fmaxf(cm0, sv2[j].x); cm1 = fmaxf(cm1, sv2[j].y); }
      float mn0 = fmaxf(m0, cm0), mn1 = fmaxf(m1, cm1);
      float al0 = __expf(m0 - mn0), al1 = __expf(m1 - mn1);
      float ps0 = 0.f, ps1 = 0.f;
      #pragma unroll
      for (int j = 0; j < 8; ++j) {
        float e0 = __expf(sv2[j].x - mn0); ps0 += e0;
        float e1 = __expf(sv2[j].y - mn1); ps1 += e1;
        sv2[j] = (v2f){e0, e1};
      }
      l0 = l0 * al0 + ps0; m0 = mn0;
      l1 = l1 * al1 + ps1; m1 = mn1;
      v2f al2 = (v2f){al0, al1};
      #pragma unroll
      for (int i = 0; i < 8; ++i) {
        v2f A0 = o2[4*i+0] * al2;
        v2f A1 = o2[4*i+1] * al2;
        v2f A2 = o2[4*i+2] * al2;
        v2f A3 = o2[4*i+3] * al2;
        #pragma unroll
        for (int j = 0; j < 8; ++j) {
          float4 vv = *(const float4*)&Vt[(c0 + j) * 32 + 4 * i];   // shared read
          A0 += sv2[j] * (v2f){vv.x, vv.x};
          A1 += sv2[j] * (v2f){vv.y, vv.y};
          A2 += sv2[j] * (v2f){vv.z, vv.z};
          A3 += sv2[j] * (v2f){vv.w, vv.w};
        }
        o2[4*i+0] = A0; o2[4*i+1] = A1; o2[4*i+2] = A2; o2[4*i+3] = A3;
      }
    }
  }
  size_t rb0 = (((size_t)(b * 2 + h)) * 2 + seg) * TT + tq0;
  size_t rb1 = rb0 + 256;
  float* op0 = po + rb0 * 32;
  float* op1 = po + rb1 * 32;
  #pragma unroll
  for (int i = 0; i < 8; ++i) {
    float4 s0; s0.x = o2[4*i+0].x; s0.y = o2[4*i+1].x; s0.z = o2[4*i+2].x; s0.w = o2[4*i+3].x;
    float4 s1; s1.x = o2[4*i+0].y; s1.y = o2[4*i+1].y; s1.z = o2[4*i+2].y; s1.w = o2[4*i+3].y;
    ((float4*)op0)[i] = s0;
    ((float4*)op1)[i] = s1;
  }
  ml[rb0 * 2 + 0] = m0; ml[rb0 * 2 + 1] = l0;
  ml[rb1 * 2 + 0] = m1; ml[rb1 * 2 + 1] = l1;
}

// ---------------- combine the two key-segments -> attnO [b][t][64] ----------------
extern "C" __global__ void __launch_bounds__(256)
k_attn_comb(const float* po, const float* ml, float* attnO) {
  int row = blockIdx.x * 256 + threadIdx.x;   // 0 .. 64*2*1024-1
  int bh = row >> 10;
  int t  = row & 1023;
  int b = bh >> 1, h = bh & 1;
  size_t r0 = ((size_t)bh * 2 + 0) * TT + t;
  size_t r1 = ((size_t)bh * 2 + 1) * TT + t;
  float m0 = ml[r0 * 2], l0 = ml[r0 * 2 + 1];
  float m1 = ml[r1 * 2], l1 = ml[r1 * 2 + 1];
  float m = fmaxf(m0, m1);
  float w0 = __expf(m0 - m), w1 = __expf(m1 - m);
  float inv = 1.f / (w0 * l0 + w1 * l1);
  w0 *= inv; w1 *= inv;
  const float4* p0 = (const float4*)(po + r0 * 32);
  const float4* p1 = (const float4*)(po + r1 * 32);
  float* op = attnO + ((size_t)b * TT + t) * 64 + h * 32;
  #pragma unroll
  for (int i = 0; i < 8; ++i) {
    float4 a = p0[i], c = p1[i], r;
    r.x = a.x * w0 + c.x * w1; r.y = a.y * w0 + c.y * w1;
    r.z = a.z * w0 + c.z * w1; r.w = a.w * w0 + c.w * w1;
    ((float4*)op)[i] = r;
  }
}

// ---------------- MHA1 output projection (K=64, G=64, 8x g-blocked) ----------------
extern "C" __global__ void __launch_bounds__(256)
k_oproj(const float* attnO, const float* out_w1, const float* out_b1, float* a1) {
  int b  = blockIdx.x >> 4;
  int t0 = (blockIdx.x & 15) << 6;
  __shared__ float al[64 * 65];
  gemm64b(attnO + ((size_t)b * TT + t0) * 64, out_w1, out_b1, al, 64, threadIdx.x,
          a1, 64, ((size_t)b * TT + t0) * 64);
}

// ---------------- MHA2: only the last query row matters -> scores s2 + values v2 ----------------
// (R8 form; R10's 8x d-blocking here cost ~45us -- reverted)
extern "C" __global__ void __launch_bounds__(256)
k_mha2kv(const float* a1, const float* in_w2, const float* in_b2,
         float* s2, float* v2) {
  int b  = blockIdx.x >> 4;
  int t0 = (blockIdx.x & 15) << 6;
  int tid = threadIdx.x;
  __shared__ float a1r[64 * 65];
  __shared__ float q2s[64];
  __shared__ float alast[64];
  if (tid < 64) alast[tid] = a1[((size_t)b * TT + (TT - 1)) * 64 + tid];
  for (int i = tid; i < 4096; i += 256) {
    int r = i >> 6, e = i & 63;
    a1r[r * 65 + e] = a1[((size_t)b * TT + t0 + r) * 64 + e];
  }
  __syncthreads();
  if (tid < 64) {
    float acc = in_b2[tid];
    const float* wr = in_w2 + (size_t)tid * 64;
    #pragma unroll
    for (int e = 0; e < 64; ++e) acc += alast[e] * wr[e];
    q2s[tid] = acc;
  }
  __syncthreads();
  int tt = tid & 63;
  int role = tid >> 6;
  const float* ar = &a1r[tt * 65];
  const float scale = 0.17677669529663687f;
  if (role < 2) {
    float s = 0.f;
    for (int d = 0; d < 32; ++d) {
      int row = 64 + role * 32 + d;
      const float* wr = in_w2 + (size_t)row * 64;
      float acc = in_b2[row];
      #pragma unroll
      for (int e = 0; e < 64; ++e) acc += ar[e] * wr[e];
      s += q2s[row - 64] * acc;
    }
    s2[((size_t)b * 2 + role) * TT + t0 + tt] = s * scale;
  } else {
    int half = role - 2;
    for (int d = 0; d < 32; ++d) {
      int vd = half * 32 + d;
      int row = 128 + vd;
      const float* wr = in_w2 + (size_t)row * 64;
      float acc = in_b2[row];
      #pragma unroll
      for (int e = 0; e < 64; ++e) acc += ar[e] * wr[e];
      v2[((size_t)b * TT + t0 + tt) * 64 + vd] = acc;
    }
  }
}

// ---------------- MHA2 softmax+PV, out-proj, final MLP ----------------
extern "C" __global__ void __launch_bounds__(256)
k_final(const float* s2, const float* v2,
        const float* out_w2, const float* out_b2,
        const float* w_l, const float* b_l,
        const float* w_l1, const float* b_l1,
        float* out) {
  int b = blockIdx.x;
  int tid = threadIdx.x;
  __shared__ float sm[2 * 1024];
  __shared__ float red[8];
  __shared__ float invl[2];
  __shared__ float opart[4 * 64];
  __shared__ float of[64];
  __shared__ float a2[64];
  __shared__ float hbuf[32];
  __shared__ int bad;
  if (tid == 0) bad = 0;
  for (int i = tid; i < 2048; i += 256) sm[i] = s2[(size_t)b * 2 * TT + i];
  __syncthreads();
  int lane = tid & 63;
  int wid = tid >> 6;
  for (int hh = 0; hh < 2; ++hh) {
    float mx = -1e30f;
    for (int i = tid; i < 1024; i += 256) mx = fmaxf(mx, sm[hh * 1024 + i]);
    #pragma unroll
    for (int off = 32; off > 0; off >>= 1) mx = fmaxf(mx, __shfl_down(mx, off));
    if (lane == 0) red[wid] = mx;
    __syncthreads();
    if (tid == 0) red[4] = fmaxf(fmaxf(red[0], red[1]), fmaxf(red[2], red[3]));
    __syncthreads();
    mx = red[4];
    float s = 0.f;
    for (int i = tid; i < 1024; i += 256) {
      float e = __expf(sm[hh * 1024 + i] - mx);
      sm[hh * 1024 + i] = e;
      s += e;
    }
    #pragma unroll
    for (int off = 32; off > 0; off >>= 1) s += __shfl_down(s, off);
    if (lane == 0) red[wid] = s;
    __syncthreads();
    if (tid == 0) invl[hh] = 1.f / (red[0] + red[1] + red[2] + red[3]);
    __syncthreads();
  }
  {
    int dp = tid & 63;
    int part = tid >> 6;
    int hh = dp >> 5;
    float acc = 0.f;
    for (int t = part * 256; t < part * 256 + 256; ++t)
      acc += sm[hh * 1024 + t] * v2[((size_t)b * TT + t) * 64 + dp];
    opart[part * 64 + dp] = acc;
  }
  __syncthreads();
  if (tid < 64) {
    float o = (opart[tid] + opart[64 + tid] + opart[128 + tid] + opart[192 + tid]) * invl[tid >> 5];
    of[tid] = o;
    if (!finitef(o)) bad = 1;
  }
  __syncthreads();
  if (tid < 64) {
    float acc = out_b2[tid];
    const float* wr = out_w2 + (size_t)tid * 64;
    #pragma unroll
    for (int d = 0; d < 64; ++d) acc += of[d] * wr[d];
    a2[tid] = acc;
  }
  __syncthreads();
  if (tid < 32) {
    float acc = b_l[tid];
    const float* wr = w_l + (size_t)tid * 64;
    #pragma unroll
    for (int e = 0; e < 64; ++e) acc += a2[e] * wr[e];
    hbuf[tid] = fmaxf(acc, 0.f);
  }
  __syncthreads();
  if (tid == 0) {
    float acc = b_l1[0];
    #pragma unroll
    for (int j = 0; j < 32; ++j) acc += hbuf[j] * w_l1[j];
    out[b] = bad ? 777.0f : acc;
  }
}

extern "C" void kernel_launch(void* const* d_in, const int* in_sizes, int n_in,
                              void* d_out, int out_size, void* d_ws, size_t ws_size,
                              hipStream_t stream) {
  const int*   atom_idx  = (const int*)d_in[0];
  const float* bond_dist = (const float*)d_in[1];
  const float* emb       = (const float*)d_in[2];
  const float* w_ih0     = (const float*)d_in[3];
  const float* w_hh0     = (const float*)d_in[4];
  const float* b_ih0     = (const float*)d_in[5];
  const float* b_hh0     = (const float*)d_in[6];
  const float* w_ih1     = (const float*)d_in[7];
  const float* w_hh1     = (const float*)d_in[8];
  const float* b_ih1     = (const float*)d_in[9];
  const float* b_hh1     = (const float*)d_in[10];
  const float* in_w1     = (const float*)d_in[11];
  const float* in_b1     = (const float*)d_in[12];
  const float* out_w1    = (const float*)d_in[13];
  const float* out_b1    = (const float*)d_in[14];
  const float* in_w2     = (const float*)d_in[15];
  const float* in_b2     = (const float*)d_in[16];
  const float* out_w2    = (const float*)d_in[17];
  const float* out_b2    = (const float*)d_in[18];
  const float* w_l       = (const float*)d_in[19];
  const float* b_l       = (const float*)d_in[20];
  const float* w_l1      = (const float*)d_in[21];
  const float* b_l1      = (const float*)d_in[22];

  // Arena plan (84,410,368 B total), all f32:
  //   X @ 0        (50.3 MB): xw0 -> {q,k,v | po} -> v2
  //   A @ 50331648 (16.8 MB): attnO
  //   B @ 67108864 (16.8 MB): g1 -> ml (2MB, during attn) -> a1
  //   D @ 83886080 (0.5 MB):  s2
  char* ws = (char*)d_ws;
  float* X  = (float*)(ws);
  float* A  = (float*)(ws + 50331648);
  float* Bq = (float*)(ws + 67108864);
  float* D  = (float*)(ws + 83886080);
  float* q1 = X;
  float* k1 = X + 4194304;
  float* v1 = X + 8388608;
  float* po = (float*)(ws + 16777216);   // [bh][seg][t][32] = 33,554,432 B, ends exactly at A
  float* ml = Bq;                        // [bh][seg][t][2]  = 2 MB, dead before oproj writes a1

  k_xw0      <<<dim3(1024), dim3(256), 0, stream>>>(atom_idx, bond_dist, emb, w_ih0, b_ih0, X);
  k_grufused <<<dim3(64),   dim3(192), 0, stream>>>(X, w_hh0, b_hh0, w_ih1, b_ih1, w_hh1, b_hh1, Bq);
  k_qkv      <<<dim3(1024), dim3(256), 0, stream>>>(Bq, in_w1, in_b1, q1, k1, v1);
  k_attn     <<<dim3(512),  dim3(256), 0, stream>>>(q1, k1, v1, po, ml);
  k_attn_comb<<<dim3(512),  dim3(256), 0, stream>>>(po, ml, A);
  k_oproj    <<<dim3(1024), dim3(256), 0, stream>>>(A, out_w1, out_b1, Bq);
  k_mha2kv   <<<dim3(1024), dim3(256), 0, stream>>>(Bq, in_w2, in_b2, D, X);
  k_final    <<<dim3(64),   dim3(256), 0, stream>>>(D, X, out_w2, out_b2, w_l, b_l, w_l1, b_l1, (float*)d_out);
}